// Round 5
// baseline (548.215 us; speedup 1.0000x reference)
//
#include <hip/hip_runtime.h>
#include <cstdint>

#define TT 50
#define II 5
#define PRED 12

typedef _Float16 f16;
typedef _Float16 f16x8 __attribute__((ext_vector_type(8)));
typedef float f32x4 __attribute__((ext_vector_type(4)));

#define K1 1.4426950408889634f
#define K2 2.8853900817779268f

// fused-rational LSTM cell: 5 exp + 2 rcp
__device__ __forceinline__ float cellact(float xi, float xf, float xg, float xo, float& c) {
    float ea = __builtin_amdgcn_exp2f(xi * -K1);
    float ef = __builtin_amdgcn_exp2f(xf * -K1);
    float eg = __builtin_amdgcn_exp2f(xg *  K2);
    float eo = __builtin_amdgcn_exp2f(xo * -K1);
    float a1 = 1.f + ea, a2 = 1.f + ef, a3 = eg + 1.f, a4 = eg - 1.f;
    float t1 = a1 * a3;
    float cn = fmaf(c, t1, a4 * a2) * __builtin_amdgcn_rcpf(t1 * a2);
    c = cn;
    float cc = fminf(fmaxf(cn, -15.f), 15.f);
    float ec = __builtin_amdgcn_exp2f(cc * K2);
    return (ec - 1.f) * __builtin_amdgcn_rcpf((1.f + eo) * (ec + 1.f));
}

// input chunk (logical chunk 16): [v0..v4, 1, 0, 0]
__device__ __forceinline__ void write_x5(unsigned char* sb, int sl,
                                         float v0, float v1, float v2, float v3, float v4) {
    union { f16 h[8]; uint4 u; } pk;
    pk.h[0] = (f16)v0; pk.h[1] = (f16)v1; pk.h[2] = (f16)v2;
    pk.h[3] = (f16)v3; pk.h[4] = (f16)v4;
    pk.h[5] = (f16)1.f; pk.h[6] = (f16)0.f; pk.h[7] = (f16)0.f;
    int phys = 16 ^ (2 * (sl & 15));
    *(uint4*)(sb + sl * 512 + phys * 16) = pk.u;
}

// MFMA-wave weight fragments: wave mw owns m-tiles mt = mw*8 + r (gate rows
// mt*16..mt*16+15). A[m=cl][k=q*8+j] of Wcat[g][k]: k<128 Whh, 128..132 Wih,
// 133 bias, else 0.
__device__ __forceinline__ void load_weights8(const float* __restrict__ Wih,
                                              const float* __restrict__ Whh,
                                              const float* __restrict__ bih,
                                              const float* __restrict__ bhh,
                                              f16x8 (&wr)[8][5], int mw, int cl, int q) {
    #pragma unroll
    for (int r = 0; r < 8; ++r) {
        int g = (mw * 8 + r) * 16 + cl;
        const float* row = Whh + g * 128 + q * 8;
        #pragma unroll
        for (int kc = 0; kc < 4; ++kc) {
            float4 a = *(const float4*)(row + kc * 32);
            float4 b = *(const float4*)(row + kc * 32 + 4);
            f16x8 t;
            t[0] = (f16)a.x; t[1] = (f16)a.y; t[2] = (f16)a.z; t[3] = (f16)a.w;
            t[4] = (f16)b.x; t[5] = (f16)b.y; t[6] = (f16)b.z; t[7] = (f16)b.w;
            wr[r][kc] = t;
        }
        f16x8 t;
        #pragma unroll
        for (int j = 0; j < 8; ++j) {
            int k = 128 + q * 8 + j;
            float v = 0.f;
            if (k < 133)       v = Wih[g * 5 + (k - 128)];
            else if (k == 133) v = bih[g] + bhh[g];
            t[j] = (f16)v;
        }
        wr[r][4] = t;
    }
}

// gates[g][s] -> LDS as [s][512 f32], 16B chunks swizzled phys = ch ^ (s&7)
__device__ __forceinline__ void mfma_gates(const unsigned char* sbuf, float* gbuf,
                                           const f16x8 (&wr)[8][5], int mw, int cl, int q) {
    f32x4 acc[8];
    #pragma unroll
    for (int r = 0; r < 8; ++r) acc[r] = (f32x4){0.f, 0.f, 0.f, 0.f};
    #pragma unroll
    for (int kc = 0; kc < 5; ++kc) {
        int phys = (kc * 4 + q) ^ (2 * cl);
        f16x8 bf = *(const f16x8*)(sbuf + cl * 512 + phys * 16);
        #pragma unroll
        for (int r = 0; r < 8; ++r)
            acc[r] = __builtin_amdgcn_mfma_f32_16x16x32_f16(wr[r][kc], bf, acc[r], 0, 0, 0);
    }
    unsigned char* grow = (unsigned char*)gbuf + cl * 2048;
    #pragma unroll
    for (int r = 0; r < 8; ++r) {
        int ch = (mw * 8 + r) * 4 + q;
        *(f32x4*)(grow + ((ch ^ (cl & 7)) * 16)) = acc[r];
    }
}

__device__ __forceinline__ void read_gates(const float* gbuf, int sloc, int j0,
                                           float (&gv)[4][8]) {
    const unsigned char* grow = (const unsigned char*)gbuf + sloc * 2048;
    #pragma unroll
    for (int tix = 0; tix < 4; ++tix) {
        int c0 = tix * 32 + (j0 >> 2);
        f32x4 a = *(const f32x4*)(grow + ((c0 ^ (sloc & 7)) * 16));
        f32x4 b = *(const f32x4*)(grow + (((c0 + 1) ^ (sloc & 7)) * 16));
        gv[tix][0] = a[0]; gv[tix][1] = a[1]; gv[tix][2] = a[2]; gv[tix][3] = a[3];
        gv[tix][4] = b[0]; gv[tix][5] = b[1]; gv[tix][6] = b[2]; gv[tix][7] = b[3];
    }
}

// ---------------- wave-specialized LSTM kernel ----------------
// 512 blocks x 512 threads, 32 samples/block (A=0..15, B=16..31).
// Waves 0-3: MFMA only (gates GEMM). Waves 4-7: trans/VALU only (cell update).
// Each SIMD hosts one wave of each role -> matrix pipe hides under trans pipe.
// Steady state: P1 [mfma gatesB(t) | act gatesA(t)->stateA]  barrier
//               P2 [mfma gatesA(t+1) | act gatesB(t)->stateB] barrier
__global__ __launch_bounds__(512, 2)
void lstm_kernel(const float* __restrict__ x,
                 const float* __restrict__ eWih, const float* __restrict__ eWhh,
                 const float* __restrict__ ebih, const float* __restrict__ ebhh,
                 const float* __restrict__ dWih, const float* __restrict__ dWhh,
                 const float* __restrict__ dbih, const float* __restrict__ dbhh,
                 const float* __restrict__ linW, const float* __restrict__ linB,
                 float* __restrict__ out) {
    __shared__ __align__(16) unsigned char stateA[16 * 512];   // 8 KB
    __shared__ __align__(16) unsigned char stateB[16 * 512];
    __shared__ __align__(16) float gatesA[16 * 512];           // 32 KB
    __shared__ __align__(16) float gatesB[16 * 512];
    __shared__ float pp[2][2][4][16][2];                       // [grp][parity][u][s][2]

    const int tid  = threadIdx.x;
    const int lane = tid & 63;
    const int w    = tid >> 6;
    const int q    = lane >> 4;
    const int cl   = lane & 15;
    const int s0   = blockIdx.x * 32;
    const bool mf  = (w < 4);
    const int mw   = w;          // MFMA wave id
    const int u    = w - 4;      // ACT wave id
    const int j0   = u * 32 + q * 8;           // ACT: hidden rows j0..j0+7
    const int physh = (u * 4 + q) ^ (2 * cl);  // ACT h-write chunk (sample=cl row)

    f16x8 wr[8][5];
    float creg[2][8];
    #pragma unroll
    for (int a = 0; a < 2; ++a)
        #pragma unroll
        for (int b = 0; b < 8; ++b) creg[a][b] = 0.f;
    float w0r[8], w1r[8];
    float velA0 = 0, velA1 = 0, scA0 = 0, scA1 = 0, scA2 = 0;
    float velB0 = 0, velB1 = 0, scB0 = 0, scB1 = 0, scB2 = 0;
    float lb0 = 0, lb1 = 0;

    if (mf) load_weights8(eWih, eWhh, ebih, ebhh, wr, mw, cl, q);

    // zero both state buffers (h0 = 0 + zero pad chunks)
    {
        uint4 z{0, 0, 0, 0};
        ((uint4*)stateA)[tid] = z;
        ((uint4*)stateB)[tid] = z;
    }
    __syncthreads();
    if ((w == 4 || w == 5) && lane < 16) {     // x(0) for both groups
        int sg = s0 + (w - 4) * 16 + lane;
        const float* xr = x + (size_t)sg * (TT * II);
        write_x5((w == 4) ? stateA : stateB, lane, xr[0], xr[1], xr[2], xr[3], xr[4]);
    }
    __syncthreads();
    if (mf) mfma_gates(stateA, gatesA, wr, mw, cl, q);   // gatesA(0)
    __syncthreads();

    // ===================== encoder, t = 0..48 =====================
    #pragma unroll 1
    for (int t = 0; t < TT - 1; ++t) {
        // P1: mfma gatesB(t) | act_A(t) -> stateA(h(t+1), x(t+1))
        if (mf) {
            mfma_gates(stateB, gatesB, wr, mw, cl, q);
        } else {
            float xv0 = 0, xv1 = 0, xv2 = 0, xv3 = 0, xv4 = 0;
            if (w == 4 && lane < 16) {
                const float* xr = x + (size_t)(s0 + lane) * (TT * II) + (t + 1) * II;
                xv0 = xr[0]; xv1 = xr[1]; xv2 = xr[2]; xv3 = xr[3]; xv4 = xr[4];
            }
            float gv[4][8];
            read_gates(gatesA, cl, j0, gv);
            union { f16 h[8]; uint4 uu; } pk;
            #pragma unroll
            for (int jj = 0; jj < 8; ++jj)
                pk.h[jj] = (f16)cellact(gv[0][jj], gv[1][jj], gv[2][jj], gv[3][jj], creg[0][jj]);
            *(uint4*)(stateA + cl * 512 + physh * 16) = pk.uu;
            if (w == 4 && lane < 16) write_x5(stateA, lane, xv0, xv1, xv2, xv3, xv4);
        }
        __syncthreads();
        // P2: mfma gatesA(t+1) | act_B(t) -> stateB
        if (mf) {
            mfma_gates(stateA, gatesA, wr, mw, cl, q);
        } else {
            float xv0 = 0, xv1 = 0, xv2 = 0, xv3 = 0, xv4 = 0;
            if (w == 5 && lane < 16) {
                const float* xr = x + (size_t)(s0 + 16 + lane) * (TT * II) + (t + 1) * II;
                xv0 = xr[0]; xv1 = xr[1]; xv2 = xr[2]; xv3 = xr[3]; xv4 = xr[4];
            }
            float gv[4][8];
            read_gates(gatesB, cl, j0, gv);
            union { f16 h[8]; uint4 uu; } pk;
            #pragma unroll
            for (int jj = 0; jj < 8; ++jj)
                pk.h[jj] = (f16)cellact(gv[0][jj], gv[1][jj], gv[2][jj], gv[3][jj], creg[1][jj]);
            *(uint4*)(stateB + cl * 512 + physh * 16) = pk.uu;
            if (w == 5 && lane < 16) write_x5(stateB, lane, xv0, xv1, xv2, xv3, xv4);
        }
        __syncthreads();
    }
    // t=49 P1: mfma gatesB(49) | act_A(49) (no x write)
    if (mf) {
        mfma_gates(stateB, gatesB, wr, mw, cl, q);
    } else {
        float gv[4][8];
        read_gates(gatesA, cl, j0, gv);
        union { f16 h[8]; uint4 uu; } pk;
        #pragma unroll
        for (int jj = 0; jj < 8; ++jj)
            pk.h[jj] = (f16)cellact(gv[0][jj], gv[1][jj], gv[2][jj], gv[3][jj], creg[0][jj]);
        *(uint4*)(stateA + cl * 512 + physh * 16) = pk.uu;
    }
    __syncthreads();
    // t=49 P2': mfma waves load dec weights/scalars | act_B(49)
    if (mf) {
        load_weights8(dWih, dWhh, dbih, dbhh, wr, mw, cl, q);
        const float* xeA = x + (size_t)(s0 + cl) * (TT * II) + (TT - 1) * II;
        velA0 = xeA[0]; velA1 = xeA[1]; scA0 = xeA[2]; scA1 = xeA[3]; scA2 = xeA[4];
        const float* xeB = x + (size_t)(s0 + 16 + cl) * (TT * II) + (TT - 1) * II;
        velB0 = xeB[0]; velB1 = xeB[1]; scB0 = xeB[2]; scB1 = xeB[3]; scB2 = xeB[4];
        lb0 = linB[0]; lb1 = linB[1];
    } else {
        float gv[4][8];
        read_gates(gatesB, cl, j0, gv);
        union { f16 h[8]; uint4 uu; } pk;
        #pragma unroll
        for (int jj = 0; jj < 8; ++jj)
            pk.h[jj] = (f16)cellact(gv[0][jj], gv[1][jj], gv[2][jj], gv[3][jj], creg[1][jj]);
        *(uint4*)(stateB + cl * 512 + physh * 16) = pk.uu;
        #pragma unroll
        for (int jj = 0; jj < 8; ++jj) {
            w0r[jj] = linW[j0 + jj];
            w1r[jj] = linW[128 + j0 + jj];
        }
    }
    __syncthreads();
    // dec prologue: x5_A(dec_in0) + gatesA(dec 0)
    if (mf) {
        if (q == 0) write_x5(stateA, cl, velA0, velA1, scA0, scA1, scA2);
        mfma_gates(stateA, gatesA, wr, mw, cl, q);
    }
    __syncthreads();

    // ===================== decoder, d = 0..11 =====================
    #pragma unroll 1
    for (int d = 0; d < PRED; ++d) {
        // P1: mfma gatesB(d) [x5_B from velB or pred_B(d-1)] | act_A(d)
        if (mf) {
            float p0, p1;
            if (d == 0) { p0 = velB0; p1 = velB1; }
            else {
                int pr = (d - 1) & 1;
                p0 = lb0; p1 = lb1;
                #pragma unroll
                for (int uu = 0; uu < 4; ++uu) {
                    p0 += pp[1][pr][uu][cl][0];
                    p1 += pp[1][pr][uu][cl][1];
                }
                if (mw == 0 && q == 0) {
                    float2 o2; o2.x = p0; o2.y = p1;
                    *(float2*)(out + (size_t)(s0 + 16 + cl) * (PRED * 2) + (d - 1) * 2) = o2;
                }
            }
            if (q == 0) write_x5(stateB, cl, p0, p1, scB0, scB1, scB2);
            mfma_gates(stateB, gatesB, wr, mw, cl, q);
        } else {
            float gv[4][8];
            read_gates(gatesA, cl, j0, gv);
            union { f16 h[8]; uint4 uu; } pk;
            float np0 = 0.f, np1 = 0.f;
            #pragma unroll
            for (int jj = 0; jj < 8; ++jj) {
                float hv = cellact(gv[0][jj], gv[1][jj], gv[2][jj], gv[3][jj], creg[0][jj]);
                np0 = fmaf(hv, w0r[jj], np0);
                np1 = fmaf(hv, w1r[jj], np1);
                pk.h[jj] = (f16)hv;
            }
            *(uint4*)(stateA + cl * 512 + physh * 16) = pk.uu;
            np0 += __shfl_xor(np0, 16); np0 += __shfl_xor(np0, 32);
            np1 += __shfl_xor(np1, 16); np1 += __shfl_xor(np1, 32);
            if (lane < 16) {
                pp[0][d & 1][u][cl][0] = np0;
                pp[0][d & 1][u][cl][1] = np1;
            }
        }
        __syncthreads();
        // P2: mfma gatesA(d+1) [x5_A from pred_A(d)] + out_A(d) | act_B(d)
        if (mf) {
            int pr = d & 1;
            float p0 = lb0, p1 = lb1;
            #pragma unroll
            for (int uu = 0; uu < 4; ++uu) {
                p0 += pp[0][pr][uu][cl][0];
                p1 += pp[0][pr][uu][cl][1];
            }
            if (mw == 0 && q == 0) {
                float2 o2; o2.x = p0; o2.y = p1;
                *(float2*)(out + (size_t)(s0 + cl) * (PRED * 2) + d * 2) = o2;
            }
            if (q == 0) write_x5(stateA, cl, p0, p1, scA0, scA1, scA2);
            mfma_gates(stateA, gatesA, wr, mw, cl, q);
        } else {
            float gv[4][8];
            read_gates(gatesB, cl, j0, gv);
            union { f16 h[8]; uint4 uu; } pk;
            float np0 = 0.f, np1 = 0.f;
            #pragma unroll
            for (int jj = 0; jj < 8; ++jj) {
                float hv = cellact(gv[0][jj], gv[1][jj], gv[2][jj], gv[3][jj], creg[1][jj]);
                np0 = fmaf(hv, w0r[jj], np0);
                np1 = fmaf(hv, w1r[jj], np1);
                pk.h[jj] = (f16)hv;
            }
            *(uint4*)(stateB + cl * 512 + physh * 16) = pk.uu;
            np0 += __shfl_xor(np0, 16); np0 += __shfl_xor(np0, 32);
            np1 += __shfl_xor(np1, 16); np1 += __shfl_xor(np1, 32);
            if (lane < 16) {
                pp[1][d & 1][u][cl][0] = np0;
                pp[1][d & 1][u][cl][1] = np1;
            }
        }
        __syncthreads();
    }
    // tail: pred_B(11)
    if (mf && mw == 0 && q == 0) {
        float p0 = lb0, p1 = lb1;
        #pragma unroll
        for (int uu = 0; uu < 4; ++uu) {
            p0 += pp[1][(PRED - 1) & 1][uu][cl][0];
            p1 += pp[1][(PRED - 1) & 1][uu][cl][1];
        }
        float2 o2; o2.x = p0; o2.y = p1;
        *(float2*)(out + (size_t)(s0 + 16 + cl) * (PRED * 2) + (PRED - 1) * 2) = o2;
    }
}

extern "C" void kernel_launch(void* const* d_in, const int* in_sizes, int n_in,
                              void* d_out, int out_size, void* d_ws, size_t ws_size,
                              hipStream_t stream) {
    (void)in_sizes; (void)n_in; (void)out_size; (void)d_ws; (void)ws_size;
    const float* x    = (const float*)d_in[0];
    const float* eWih = (const float*)d_in[1];
    const float* eWhh = (const float*)d_in[2];
    const float* ebih = (const float*)d_in[3];
    const float* ebhh = (const float*)d_in[4];
    const float* dWih = (const float*)d_in[5];
    const float* dWhh = (const float*)d_in[6];
    const float* dbih = (const float*)d_in[7];
    const float* dbhh = (const float*)d_in[8];
    const float* linW = (const float*)d_in[9];
    const float* linB = (const float*)d_in[10];

    lstm_kernel<<<512, 512, 0, stream>>>(x, eWih, eWhh, ebih, ebhh,
                                         dWih, dWhh, dbih, dbhh,
                                         linW, linB, (float*)d_out);
}

// Round 6
// 421.307 us; speedup vs baseline: 1.3012x; 1.3012x over previous
//
#include <hip/hip_runtime.h>
#include <cstdint>

#define TT 50
#define II 5
#define PRED 12

typedef _Float16 f16;
typedef _Float16 f16x8 __attribute__((ext_vector_type(8)));
typedef float f32x4 __attribute__((ext_vector_type(4)));

#define K1 1.4426950408889634f
#define K2 2.8853900817779268f

// fused-rational LSTM cell: 5 exp + 2 rcp
__device__ __forceinline__ float cellact(float xi, float xf, float xg, float xo, float& c) {
    float ea = __builtin_amdgcn_exp2f(xi * -K1);
    float ef = __builtin_amdgcn_exp2f(xf * -K1);
    float eg = __builtin_amdgcn_exp2f(xg *  K2);
    float eo = __builtin_amdgcn_exp2f(xo * -K1);
    float a1 = 1.f + ea, a2 = 1.f + ef, a3 = eg + 1.f, a4 = eg - 1.f;
    float t1 = a1 * a3;
    float cn = fmaf(c, t1, a4 * a2) * __builtin_amdgcn_rcpf(t1 * a2);
    c = cn;
    float cc = fminf(fmaxf(cn, -15.f), 15.f);
    float ec = __builtin_amdgcn_exp2f(cc * K2);
    return (ec - 1.f) * __builtin_amdgcn_rcpf((1.f + eo) * (ec + 1.f));
}

// row swizzle: chunk ch of sample-row sl -> phys chunk (2-way-conflict max)
__device__ __forceinline__ int swz(int ch, int sl) {
    return ch ^ (2 * sl) ^ (sl >> 3);
}

// input chunk (logical chunk 16): [v0..v4, 1, 0, 0]
__device__ __forceinline__ void write_x5(unsigned char* sb, int sl,
                                         float v0, float v1, float v2, float v3, float v4) {
    union { f16 h[8]; uint4 u; } pk;
    pk.h[0] = (f16)v0; pk.h[1] = (f16)v1; pk.h[2] = (f16)v2;
    pk.h[3] = (f16)v3; pk.h[4] = (f16)v4;
    pk.h[5] = (f16)1.f; pk.h[6] = (f16)0.f; pk.h[7] = (f16)0.f;
    *(uint4*)(sb + sl * 512 + swz(16, sl) * 16) = pk.u;
}

// weight fragments: wave w owns m-tiles mt = gs*8 + w + 4*js (gs=0..3 gate,
// js=0..1 j-block). A[m=cl][k=q*8+j] of Wcat[g=mt*16+cl][k]: k<128 Whh,
// 128..132 Wih, 133 bih+bhh, else 0.  k = kc*32 + q*8 + j.
__device__ __forceinline__ void load_weights(const float* __restrict__ Wih,
                                             const float* __restrict__ Whh,
                                             const float* __restrict__ bih,
                                             const float* __restrict__ bhh,
                                             f16x8 (&wr)[4][2][5], int w, int cl, int q) {
    #pragma unroll
    for (int gs = 0; gs < 4; ++gs) {
        #pragma unroll
        for (int js = 0; js < 2; ++js) {
            int g = (gs * 8 + w + 4 * js) * 16 + cl;
            const float* row = Whh + g * 128 + q * 8;
            #pragma unroll
            for (int kc = 0; kc < 4; ++kc) {
                float4 a = *(const float4*)(row + kc * 32);
                float4 b = *(const float4*)(row + kc * 32 + 4);
                f16x8 t;
                t[0] = (f16)a.x; t[1] = (f16)a.y; t[2] = (f16)a.z; t[3] = (f16)a.w;
                t[4] = (f16)b.x; t[5] = (f16)b.y; t[6] = (f16)b.z; t[7] = (f16)b.w;
                wr[gs][js][kc] = t;
            }
            f16x8 t;
            #pragma unroll
            for (int j = 0; j < 8; ++j) {
                int k = 128 + q * 8 + j;
                float v = 0.f;
                if (k < 133)       v = Wih[g * 5 + (k - 128)];
                else if (k == 133) v = bih[g] + bhh[g];
                t[j] = (f16)v;
            }
            wr[gs][js][4] = t;
        }
    }
}

// gates GEMM for all 16 samples: 5 B-frag reads, 40 MFMAs
__device__ __forceinline__ void do_mfma(const unsigned char* cur, const f16x8 (&wr)[4][2][5],
                                        f32x4 (&acc)[4][2], int cl, int q) {
    #pragma unroll
    for (int kc = 0; kc < 5; ++kc) {
        f16x8 bf = *(const f16x8*)(cur + cl * 512 + swz(kc * 4 + q, cl) * 16);
        #pragma unroll
        for (int gs = 0; gs < 4; ++gs)
            #pragma unroll
            for (int js = 0; js < 2; ++js)
                acc[gs][js] = __builtin_amdgcn_mfma_f32_16x16x32_f16(wr[gs][js][kc], bf, acc[gs][js], 0, 0, 0);
    }
}

// ---------------- LSTM kernel: 1024 blocks x 256 threads ----------------
// 16 samples/block; wave w handles j-blocks {w, w+4} (all 4 gates -> act is
// register-local); 2 blocks/CU => each SIMD hosts 2 waves from DIFFERENT
// blocks with independent barrier domains -> one block's MFMA phase fills
// the other's trans burst / barrier drain.
// NOTE: __launch_bounds__ 2nd arg behaves as min-workgroups-per-CU on this
// toolchain (R2: (512,4)->64 VGPR, R5: (512,2)->128 VGPR). (256,2) gives a
// 256-reg budget under either interpretation.
__global__ __launch_bounds__(256, 2)
void lstm_kernel(const float* __restrict__ x,
                 const float* __restrict__ eWih, const float* __restrict__ eWhh,
                 const float* __restrict__ ebih, const float* __restrict__ ebhh,
                 const float* __restrict__ dWih, const float* __restrict__ dWhh,
                 const float* __restrict__ dbih, const float* __restrict__ dbhh,
                 const float* __restrict__ linW, const float* __restrict__ linB,
                 float* __restrict__ out) {
    __shared__ __align__(16) unsigned char state[2][16 * 512];   // 16 KB dbuf
    __shared__ float pp[4][16][2];

    const int tid  = threadIdx.x;
    const int lane = tid & 63;
    const int w    = tid >> 6;       // wave 0..3
    const int q    = lane >> 4;      // 0..3
    const int cl   = lane & 15;      // 0..15 (= sample for B/C cols)
    const int s0   = blockIdx.x * 16;

    f16x8 wr[4][2][5];               // 160 VGPR
    load_weights(eWih, eWhh, ebih, ebhh, wr, w, cl, q);

    // h-write chunks for the 2 j-blocks this lane owns
    int physh[2], hoff = (q & 1) * 8;
    #pragma unroll
    for (int js = 0; js < 2; ++js)
        physh[js] = swz((w + 4 * js) * 2 + (q >> 1), cl);

    // zero both state buffers (h0 = 0 + zero pad chunks)
    {
        uint4 z{0, 0, 0, 0};
        uint4* p = (uint4*)&state[0][0];
        #pragma unroll
        for (int r = 0; r < 4; ++r) p[tid + r * 256] = z;
    }
    float creg[2][4];
    #pragma unroll
    for (int a = 0; a < 2; ++a)
        #pragma unroll
        for (int b = 0; b < 4; ++b) creg[a][b] = 0.f;
    const f32x4 z4 = {0.f, 0.f, 0.f, 0.f};

    __syncthreads();
    if (tid < 16) {
        const float* xr = x + (size_t)(s0 + tid) * (TT * II);
        write_x5(state[0], tid, xr[0], xr[1], xr[2], xr[3], xr[4]);
    }
    __syncthreads();

    // ===================== encoder: 1 barrier/step =====================
    #pragma unroll 1
    for (int t = 0; t < TT; ++t) {
        unsigned char* cur = state[t & 1];
        unsigned char* nxt = state[(t + 1) & 1];
        // x(t+1); t=49 re-reads x_49 (= dec_in0 exactly)
        float xv0 = 0, xv1 = 0, xv2 = 0, xv3 = 0, xv4 = 0;
        if (tid < 16) {
            int tl = (t < TT - 1) ? t + 1 : TT - 1;
            const float* xr = x + (size_t)(s0 + tid) * (TT * II) + tl * II;
            xv0 = xr[0]; xv1 = xr[1]; xv2 = xr[2]; xv3 = xr[3]; xv4 = xr[4];
        }
        f32x4 acc[4][2];
        #pragma unroll
        for (int gs = 0; gs < 4; ++gs) { acc[gs][0] = z4; acc[gs][1] = z4; }
        do_mfma(cur, wr, acc, cl, q);
        #pragma unroll
        for (int js = 0; js < 2; ++js) {
            union { f16 h[4]; uint2 u; } pk;
            #pragma unroll
            for (int idx = 0; idx < 4; ++idx)
                pk.h[idx] = (f16)cellact(acc[0][js][idx], acc[1][js][idx],
                                         acc[2][js][idx], acc[3][js][idx], creg[js][idx]);
            *(uint2*)(nxt + cl * 512 + physh[js] * 16 + hoff) = pk.u;
        }
        if (tid < 16) write_x5(nxt, tid, xv0, xv1, xv2, xv3, xv4);
        __syncthreads();   // all reads of cur done; nxt (h + x) visible
    }

    // decoder weights + linear head + static context
    load_weights(dWih, dWhh, dbih, dbhh, wr, w, cl, q);
    float w0r[2][4], w1r[2][4];
    #pragma unroll
    for (int js = 0; js < 2; ++js)
        #pragma unroll
        for (int idx = 0; idx < 4; ++idx) {
            int j = (w + 4 * js) * 16 + q * 4 + idx;
            w0r[js][idx] = linW[j];
            w1r[js][idx] = linW[128 + j];
        }
    float sc0 = 0, sc1 = 0, sc2 = 0, lb0 = 0, lb1 = 0;
    if (tid < 16) {
        const float* xr = x + (size_t)(s0 + tid) * (TT * II) + (TT - 1) * II;
        sc0 = xr[2]; sc1 = xr[3]; sc2 = xr[4];
        lb0 = linB[0]; lb1 = linB[1];
    }

    // ===================== decoder: 2 barriers/step =====================
    #pragma unroll 1
    for (int d = 0; d < PRED; ++d) {
        unsigned char* cur = state[d & 1];        // d=0 reads state[0] (TT even)
        unsigned char* nxt = state[(d + 1) & 1];
        f32x4 acc[4][2];
        #pragma unroll
        for (int gs = 0; gs < 4; ++gs) { acc[gs][0] = z4; acc[gs][1] = z4; }
        do_mfma(cur, wr, acc, cl, q);
        float p0 = 0.f, p1 = 0.f;
        #pragma unroll
        for (int js = 0; js < 2; ++js) {
            union { f16 h[4]; uint2 u; } pk;
            #pragma unroll
            for (int idx = 0; idx < 4; ++idx) {
                float hv = cellact(acc[0][js][idx], acc[1][js][idx],
                                   acc[2][js][idx], acc[3][js][idx], creg[js][idx]);
                p0 = fmaf(hv, w0r[js][idx], p0);
                p1 = fmaf(hv, w1r[js][idx], p1);
                pk.h[idx] = (f16)hv;
            }
            *(uint2*)(nxt + cl * 512 + physh[js] * 16 + hoff) = pk.u;
        }
        // reduce over q (lanes cl, cl+16, cl+32, cl+48 share sample cl)
        p0 += __shfl_xor(p0, 16); p0 += __shfl_xor(p0, 32);
        p1 += __shfl_xor(p1, 16); p1 += __shfl_xor(p1, 32);
        if (lane < 16) { pp[w][cl][0] = p0; pp[w][cl][1] = p1; }
        __syncthreads();   // h + pp visible; reads of cur done
        if (tid < 16) {
            float a0 = lb0, a1 = lb1;
            #pragma unroll
            for (int ww = 0; ww < 4; ++ww) { a0 += pp[ww][tid][0]; a1 += pp[ww][tid][1]; }
            float2 o2; o2.x = a0; o2.y = a1;
            *(float2*)(out + (size_t)(s0 + tid) * (PRED * 2) + d * 2) = o2;
            write_x5(nxt, tid, a0, a1, sc0, sc1, sc2);
        }
        __syncthreads();   // dec input visible before next step reads nxt
    }
}

extern "C" void kernel_launch(void* const* d_in, const int* in_sizes, int n_in,
                              void* d_out, int out_size, void* d_ws, size_t ws_size,
                              hipStream_t stream) {
    (void)in_sizes; (void)n_in; (void)out_size; (void)d_ws; (void)ws_size;
    const float* x    = (const float*)d_in[0];
    const float* eWih = (const float*)d_in[1];
    const float* eWhh = (const float*)d_in[2];
    const float* ebih = (const float*)d_in[3];
    const float* ebhh = (const float*)d_in[4];
    const float* dWih = (const float*)d_in[5];
    const float* dWhh = (const float*)d_in[6];
    const float* dbih = (const float*)d_in[7];
    const float* dbhh = (const float*)d_in[8];
    const float* linW = (const float*)d_in[9];
    const float* linB = (const float*)d_in[10];

    lstm_kernel<<<1024, 256, 0, stream>>>(x, eWih, eWhh, ebih, ebhh,
                                          dWih, dWhh, dbih, dbhh,
                                          linW, linB, (float*)d_out);
}